// Round 1
// baseline (185.457 us; speedup 1.0000x reference)
//
#include <hip/hip_runtime.h>
#include <math.h>

// Problem constants (fixed by the reference's setup_inputs)
#define T_STEPS 16
#define BB      128
#define VOCAB   32000
#define BEAM    4
#define BATCH   (BB / BEAM)   // 32
#define V4      (VOCAB / 4)   // 8000 float4 per row

// ---------------------------------------------------------------------------
// Insert (x, gi) into a sorted-descending top-8 list held in registers.
// Strict '>' keeps earlier-inserted elements ahead on ties (lower-index-first).
__device__ __forceinline__ void ins8(float (&v)[8], int (&ix)[8], float x, int gi) {
    if (x > v[7]) {
        v[7] = x; ix[7] = gi;
#pragma unroll
        for (int j = 7; j > 0; --j) {
            if (v[j] > v[j - 1]) {
                float tv = v[j]; v[j] = v[j - 1]; v[j - 1] = tv;
                int   ti = ix[j]; ix[j] = ix[j - 1]; ix[j - 1] = ti;
            }
        }
    }
}

__device__ __forceinline__ void ins4(float (&v)[4], int (&ix)[4], float x, int gi) {
    if (x > v[3]) {
        v[3] = x; ix[3] = gi;
#pragma unroll
        for (int j = 3; j > 0; --j) {
            if (v[j] > v[j - 1]) {
                float tv = v[j]; v[j] = v[j - 1]; v[j - 1] = tv;
                int   ti = ix[j]; ix[j] = ix[j - 1]; ix[j - 1] = ti;
            }
        }
    }
}

// ---------------------------------------------------------------------------
// Phase 1: per (step,row): sum(exp(x)) over the row + top-8 of x excluding
// pad/unk. Emits lp_top8 = x_top8 - log(sum exp) and word indices into d_ws.
// One block (256 threads) per row; coalesced float4 reads.
__global__ __launch_bounds__(256) void phase1_topk_lsm(
    const float* __restrict__ logits,
    const int*   __restrict__ pad_p,
    const int*   __restrict__ unk_p,
    float* __restrict__ topv,
    int*   __restrict__ topi)
{
    const int row = blockIdx.x;            // t*BB + r
    const int tid = threadIdx.x;
    const int pad = *pad_p, unk = *unk_p;
    const float4* __restrict__ src =
        reinterpret_cast<const float4*>(logits + (size_t)row * VOCAB);

    float v[8]; int ix[8];
#pragma unroll
    for (int k = 0; k < 8; ++k) { v[k] = -INFINITY; ix[k] = 0; }
    float tsum = 0.0f;

    for (int kv = tid; kv < V4; kv += 256) {
        float4 q = src[kv];
        int gi = kv * 4;
        float e0 = __expf(q.x), e1 = __expf(q.y);
        float e2 = __expf(q.z), e3 = __expf(q.w);
        tsum += (e0 + e1) + (e2 + e3);
        if (gi + 0 != pad && gi + 0 != unk) ins8(v, ix, q.x, gi + 0);
        if (gi + 1 != pad && gi + 1 != unk) ins8(v, ix, q.y, gi + 1);
        if (gi + 2 != pad && gi + 2 != unk) ins8(v, ix, q.z, gi + 2);
        if (gi + 3 != pad && gi + 3 != unk) ins8(v, ix, q.w, gi + 3);
    }

    // ---- wave(64)-level butterfly merge of sorted-8 lists ----
#pragma unroll
    for (int m = 1; m < 64; m <<= 1) {
        float u[8]; int ju[8];
#pragma unroll
        for (int k = 0; k < 8; ++k) {
            u[k]  = __shfl_xor(v[k],  m, 64);
            ju[k] = __shfl_xor(ix[k], m, 64);
        }
        // top-8 multiset of two sorted-desc lists: w[k] = max(v[k], u[7-k])
        float w[8]; int jw[8];
#pragma unroll
        for (int k = 0; k < 8; ++k) {
            if (u[7 - k] > v[k]) { w[k] = u[7 - k]; jw[k] = ju[7 - k]; }
            else                 { w[k] = v[k];     jw[k] = ix[k];     }
        }
        // w is bitonic -> bitonic merge to sorted descending (dist 4,2,1)
#define CE_DESC(a, b)                                                         \
        if (w[a] < w[b]) {                                                    \
            float tv = w[a]; w[a] = w[b]; w[b] = tv;                          \
            int   ti = jw[a]; jw[a] = jw[b]; jw[b] = ti;                      \
        }
        CE_DESC(0, 4) CE_DESC(1, 5) CE_DESC(2, 6) CE_DESC(3, 7)
        CE_DESC(0, 2) CE_DESC(1, 3) CE_DESC(4, 6) CE_DESC(5, 7)
        CE_DESC(0, 1) CE_DESC(2, 3) CE_DESC(4, 5) CE_DESC(6, 7)
#undef CE_DESC
#pragma unroll
        for (int k = 0; k < 8; ++k) { v[k] = w[k]; ix[k] = jw[k]; }
    }

    // wave sum reduce
#pragma unroll
    for (int m = 1; m < 64; m <<= 1) tsum += __shfl_xor(tsum, m, 64);

    // ---- cross-wave (4 waves) combine via LDS, thread 0 finalizes ----
    __shared__ float s_v[32];
    __shared__ int   s_i[32];
    __shared__ float s_s[4];
    const int wv = tid >> 6, ln = tid & 63;
    if (ln == 0) {
        s_s[wv] = tsum;
#pragma unroll
        for (int k = 0; k < 8; ++k) { s_v[wv * 8 + k] = v[k]; s_i[wv * 8 + k] = ix[k]; }
    }
    __syncthreads();
    if (tid == 0) {
        float S    = (s_s[0] + s_s[1]) + (s_s[2] + s_s[3]);
        float logS = logf(S);
        float bv[8]; int bi[8];
#pragma unroll
        for (int k = 0; k < 8; ++k) { bv[k] = s_v[k]; bi[k] = s_i[k]; }
        for (int j = 8; j < 32; ++j) ins8(bv, bi, s_v[j], s_i[j]);
        float* ov = topv + (size_t)row * 8;
        int*   oi = topi + (size_t)row * 8;
#pragma unroll
        for (int k = 0; k < 8; ++k) { ov[k] = bv[k] - logS; oi[k] = bi[k]; }
    }
}

// ---------------------------------------------------------------------------
// Phase 2: sequential 16-step beam scan per batch (32 independent blocks).
// Per step: 32 candidates (4 beams x their top-8) -> top-8 -> eos mask ->
// top-4. Records backpointers; backtrace reconstructs token sequences.
__global__ __launch_bounds__(64) void phase2_beam_scan(
    const float* __restrict__ topv,
    const int*   __restrict__ topi,
    const int*   __restrict__ eos_p,
    float* __restrict__ out)
{
    const int b   = blockIdx.x;   // batch index
    const int tid = threadIdx.x;
    const int eos = *eos_p;

    __shared__ float cv[32];
    __shared__ int   cw[32];
    __shared__ float sc[BEAM];
    __shared__ int   rb[T_STEPS][BEAM];
    __shared__ int   rw[T_STEPS][BEAM];

    if (tid < BEAM) sc[tid] = 0.0f;
    __syncthreads();

    for (int t = 0; t < T_STEPS; ++t) {
        if (tid < 32) {
            const int beam = tid >> 3;
            const int row  = t * BB + b * BEAM + beam;
            cv[tid] = topv[(size_t)row * 8 + (tid & 7)] + sc[beam];
            cw[tid] = topi[(size_t)row * 8 + (tid & 7)];
        }
        __syncthreads();
        if (tid == 0) {
            // top-8 of the 32 candidates (value desc, lower index on ties)
            float tv[8]; int tj[8];
#pragma unroll
            for (int k = 0; k < 8; ++k) { tv[k] = -INFINITY; tj[k] = 0; }
            for (int j = 0; j < 32; ++j) ins8(tv, tj, cv[j], j);
            // eos mask + top-4 of the 8
            float s4[4]; int p4[4];
#pragma unroll
            for (int k = 0; k < 4; ++k) { s4[k] = -INFINITY; p4[k] = 0; }
#pragma unroll
            for (int k = 0; k < 8; ++k) {
                float val = tv[k];
                if (cw[tj[k]] == eos) val = -INFINITY;
                ins4(s4, p4, val, k);
            }
#pragma unroll
            for (int j = 0; j < 4; ++j) {
                const int cidx = tj[p4[j]];
                rb[t][j] = cidx >> 3;      // source (old) beam
                rw[t][j] = cw[cidx];       // chosen word
                sc[j]    = s4[j];          // new cumulative scores
            }
        }
        __syncthreads();
    }

    // Backtrace + output (written as float32 values; d_out = [scores|tokens])
    if (tid < BEAM) {
        out[b * BEAM + tid] = sc[tid];
        float* tout = out + BATCH * BEAM + (size_t)(b * BEAM + tid) * (T_STEPS + 1);
        int bp = tid;
#pragma unroll
        for (int t = T_STEPS - 1; t >= 0; --t) {
            tout[t + 1] = (float)rw[t][bp];
            bp = rb[t][bp];
        }
        tout[0] = (float)eos;   // begin token (init value, never overwritten)
    }
}

// ---------------------------------------------------------------------------
extern "C" void kernel_launch(void* const* d_in, const int* in_sizes, int n_in,
                              void* d_out, int out_size, void* d_ws, size_t ws_size,
                              hipStream_t stream) {
    const float* logits = (const float*)d_in[0];
    const int*   pad_p  = (const int*)d_in[1];
    const int*   unk_p  = (const int*)d_in[2];
    const int*   eos_p  = (const int*)d_in[3];
    // d_in[4] = beam_size (hardcoded 4 to match shapes)

    // Workspace: topv [T*BB*8] f32, then topi [T*BB*8] i32  (128 KB total)
    float* topv = (float*)d_ws;
    int*   topi = (int*)(topv + T_STEPS * BB * 8);

    hipLaunchKernelGGL(phase1_topk_lsm, dim3(T_STEPS * BB), dim3(256), 0, stream,
                       logits, pad_p, unk_p, topv, topi);
    hipLaunchKernelGGL(phase2_beam_scan, dim3(BATCH), dim3(64), 0, stream,
                       topv, topi, eos_p, (float*)d_out);
}